// Round 4
// baseline (22950.038 us; speedup 1.0000x reference)
//
#include <hip/hip_runtime.h>

#define NB 64
#define NT 256
#define ND 1024
#define NH 1024
#define G4 4096
#define K2 2048

typedef short v8s __attribute__((ext_vector_type(8)));
typedef float v4f __attribute__((ext_vector_type(4)));
typedef unsigned short us4 __attribute__((ext_vector_type(4)));

__device__ __forceinline__ float bf2f(unsigned short u) {
    union { unsigned int i; float f; } v; v.i = ((unsigned int)u) << 16; return v.f;
}
__device__ __forceinline__ unsigned short f2bf(float f) {
    union { float f; unsigned int i; } v; v.f = f;
    unsigned int x = v.i;
    return (unsigned short)((x + 0x7FFFu + ((x >> 16) & 1u)) >> 16);
}

// ---- one-time: convert x (f32) -> bf16 hi/lo planes ----
__global__ void cvt_x(const float* __restrict__ x,
                      unsigned short* __restrict__ xhi,
                      unsigned short* __restrict__ xlo) {
    const int i = (blockIdx.x * blockDim.x + threadIdx.x) * 4;   // 16,777,216 exact
    const float4 a = *(const float4*)(x + i);
    us4 h, l;
    h.x = f2bf(a.x); l.x = f2bf(a.x - bf2f(h.x));
    h.y = f2bf(a.y); l.y = f2bf(a.y - bf2f(h.y));
    h.z = f2bf(a.z); l.z = f2bf(a.z - bf2f(h.z));
    h.w = f2bf(a.w); l.w = f2bf(a.w - bf2f(h.w));
    *(us4*)(xhi + i) = h;
    *(us4*)(xlo + i) = l;
}

// ---- one-time weight pack: WT[combo][n][k] bf16 hi plane + lo plane ----
// combo: 0=fw L0, 1=bw L0, 2=fw L1, 3=bw L1;  k = [Wx rows | Wh rows]
#define WLO ((size_t)4 * G4 * K2)
__global__ void transpose_pack(const float* __restrict__ fw_Wx,
                               const float* __restrict__ fw_Wh,
                               const float* __restrict__ bw_Wx,
                               const float* __restrict__ bw_Wh,
                               unsigned short* __restrict__ WT) {
    const int z = blockIdx.z;
    const int combo = z >> 1;
    const int half  = z & 1;               // 0 -> Wx, 1 -> Wh
    const int layer = combo >> 1, dirb = combo & 1;
    const float* src = half ? (dirb ? bw_Wh : fw_Wh) : (dirb ? bw_Wx : fw_Wx);
    src += (size_t)layer * ND * G4;
    const int n0 = blockIdx.x * 64, k0 = blockIdx.y * 64;
    __shared__ float tile[64][65];
    const int t = threadIdx.x;             // 256 threads
    #pragma unroll
    for (int it = 0; it < 4; ++it) {
        const int kr = it * 16 + (t >> 4);
        const int nc = (t & 15) * 4;
        const float4 v = *(const float4*)(src + (size_t)(k0 + kr) * G4 + n0 + nc);
        tile[kr][nc + 0] = v.x; tile[kr][nc + 1] = v.y;
        tile[kr][nc + 2] = v.z; tile[kr][nc + 3] = v.w;
    }
    __syncthreads();
    #pragma unroll
    for (int it = 0; it < 4; ++it) {
        const int nr = it * 16 + (t >> 4);
        const int kc = (t & 15) * 4;
        us4 h, l;
        float w0 = tile[kc + 0][nr], w1 = tile[kc + 1][nr];
        float w2 = tile[kc + 2][nr], w3 = tile[kc + 3][nr];
        h.x = f2bf(w0); l.x = f2bf(w0 - bf2f(h.x));
        h.y = f2bf(w1); l.y = f2bf(w1 - bf2f(h.y));
        h.z = f2bf(w2); l.z = f2bf(w2 - bf2f(h.z));
        h.w = f2bf(w3); l.w = f2bf(w3 - bf2f(h.w));
        const size_t o = ((size_t)combo * G4 + n0 + nr) * K2 + half * ND + k0 + kc;
        *(us4*)(WT + o) = h;
        *(us4*)(WT + WLO + o) = l;
    }
}

// ---- one super-step: combos {fw0,bw0} at scan step s, {fw1,bw1} at s-1 ----
// h_bf layout: [combo][parity][plane hi/lo][B][H]
__launch_bounds__(512)
__global__ void lstm_step(int s,
                          const unsigned short* __restrict__ xhi,
                          const unsigned short* __restrict__ xlo,
                          const int* __restrict__ lengths,
                          const float* __restrict__ fw_b,
                          const float* __restrict__ bw_b,
                          const unsigned short* __restrict__ WT,
                          float* __restrict__ c_state,              // [4][B][H]
                          float* __restrict__ h_f32,                // [4][B][H]
                          unsigned short* __restrict__ h_bf,        // [4][2][2][B][H]
                          float* __restrict__ out) {
    const int c = blockIdx.y;               // combo
    const int layer = c >> 1, dir = c & 1;
    if (layer == 0) { if (s >= NT) return; }
    else            { if (s < 1)   return; }
    const int u = (layer == 0) ? s : (s - 1);

    const int j0 = blockIdx.x * 16;
    const int tid = threadIdx.x;
    const int w = tid >> 6, lane = tid & 63;
    const int gt = w & 3, mh = w >> 2;
    const int l15 = lane & 15, g = lane >> 4;

    const int n0 = gt * NH + j0;
    const int rowb0 = mh * 32 + l15;
    const int rowb1 = rowb0 + 16;
    const size_t HP = (size_t)NB * NH;      // plane size

    // part-1 A sources (x for layer 0, layer-0 h for layer 1)
    const unsigned short *a0h, *a0l, *a1h, *a1l;
    if (layer == 0) {
        const int t = dir ? (NT - 1 - u) : u;
        const size_t o0 = (size_t)rowb0 * (NT * ND) + (size_t)t * ND + g * 8;
        const size_t o1 = (size_t)rowb1 * (NT * ND) + (size_t)t * ND + g * 8;
        a0h = xhi + o0; a0l = xlo + o0;
        a1h = xhi + o1; a1l = xlo + o1;
    } else {
        const unsigned short* ph = h_bf + (((size_t)dir * 2 + (s & 1)) * 2) * HP;
        a0h = ph + (size_t)rowb0 * NH + g * 8; a0l = a0h + HP;
        a1h = ph + (size_t)rowb1 * NH + g * 8; a1l = a1h + HP;
    }
    // part-2 A sources (own recurrent h)
    const unsigned short* ph2 = h_bf + (((size_t)c * 2 + (u & 1)) * 2) * HP;
    const unsigned short* b0h = ph2 + (size_t)rowb0 * NH + g * 8;
    const unsigned short* b0l = b0h + HP;
    const unsigned short* b1h = ph2 + (size_t)rowb1 * NH + g * 8;
    const unsigned short* b1l = b1h + HP;

    const unsigned short* bph = WT + ((size_t)c * G4 + n0 + l15) * K2 + g * 8;
    const unsigned short* bpl = bph + WLO;

    v4f acc0 = {0.f, 0.f, 0.f, 0.f}, acc1 = {0.f, 0.f, 0.f, 0.f};
    #pragma unroll 4
    for (int kk = 0; kk < 32; ++kk) {       // part 1, K = 1024
        v8s ah0 = *(const v8s*)a0h, al0 = *(const v8s*)a0l;
        v8s ah1 = *(const v8s*)a1h, al1 = *(const v8s*)a1l;
        v8s bh  = *(const v8s*)bph, bl  = *(const v8s*)bpl;
        acc0 = __builtin_amdgcn_mfma_f32_16x16x32_bf16(ah0, bh, acc0, 0, 0, 0);
        acc1 = __builtin_amdgcn_mfma_f32_16x16x32_bf16(ah1, bh, acc1, 0, 0, 0);
        acc0 = __builtin_amdgcn_mfma_f32_16x16x32_bf16(ah0, bl, acc0, 0, 0, 0);
        acc1 = __builtin_amdgcn_mfma_f32_16x16x32_bf16(ah1, bl, acc1, 0, 0, 0);
        acc0 = __builtin_amdgcn_mfma_f32_16x16x32_bf16(al0, bh, acc0, 0, 0, 0);
        acc1 = __builtin_amdgcn_mfma_f32_16x16x32_bf16(al1, bh, acc1, 0, 0, 0);
        a0h += 32; a0l += 32; a1h += 32; a1l += 32; bph += 32; bpl += 32;
    }
    #pragma unroll 4
    for (int kk = 0; kk < 32; ++kk) {       // part 2 (recurrent), K = 1024
        v8s ah0 = *(const v8s*)b0h, al0 = *(const v8s*)b0l;
        v8s ah1 = *(const v8s*)b1h, al1 = *(const v8s*)b1l;
        v8s bh  = *(const v8s*)bph, bl  = *(const v8s*)bpl;
        acc0 = __builtin_amdgcn_mfma_f32_16x16x32_bf16(ah0, bh, acc0, 0, 0, 0);
        acc1 = __builtin_amdgcn_mfma_f32_16x16x32_bf16(ah1, bh, acc1, 0, 0, 0);
        acc0 = __builtin_amdgcn_mfma_f32_16x16x32_bf16(ah0, bl, acc0, 0, 0, 0);
        acc1 = __builtin_amdgcn_mfma_f32_16x16x32_bf16(ah1, bl, acc1, 0, 0, 0);
        acc0 = __builtin_amdgcn_mfma_f32_16x16x32_bf16(al0, bh, acc0, 0, 0, 0);
        acc1 = __builtin_amdgcn_mfma_f32_16x16x32_bf16(al1, bh, acc1, 0, 0, 0);
        b0h += 32; b0l += 32; b1h += 32; b1l += 32; bph += 32; bpl += 32;
    }

    const float* bsrc = dir ? bw_b : fw_b;
    const float bias = bsrc[(size_t)layer * G4 + n0 + l15];
    #pragma unroll
    for (int r = 0; r < 4; ++r) { acc0[r] += bias; acc1[r] += bias; }

    __shared__ float glds[4][NB][16];
    #pragma unroll
    for (int r = 0; r < 4; ++r) {
        glds[gt][mh * 32 + g * 4 + r][l15]      = acc0[r];
        glds[gt][mh * 32 + 16 + g * 4 + r][l15] = acc1[r];
    }
    __syncthreads();

    for (int e = tid; e < NB * 16; e += 512) {
        const int b = e >> 4, jj = e & 15, j = j0 + jj;
        const float iv = glds[0][b][jj];
        const float fv = glds[1][b][jj];
        const float gv = glds[2][b][jj];
        const float ov = glds[3][b][jj];
        const size_t sidx = ((size_t)c * NB + b) * NH + j;
        const float cold = c_state[sidx];
        const float hold = h_f32[sidx];
        const float si = 1.f / (1.f + expf(-iv));
        const float sf = 1.f / (1.f + expf(-fv));
        const float so = 1.f / (1.f + expf(-ov));
        const float cn = sf * cold + si * tanhf(gv);
        const float hn = so * tanhf(cn);
        const bool valid = lengths[b] > u;     // un-reversed mask (reference quirk)
        const float c2 = valid ? cn : cold;
        const float h2 = valid ? hn : hold;
        c_state[sidx] = c2;
        h_f32[sidx]  = h2;
        const size_t hb = (((size_t)c * 2 + ((u + 1) & 1)) * 2) * HP + (size_t)b * NH + j;
        const unsigned short hi = f2bf(h2);
        h_bf[hb]      = hi;
        h_bf[hb + HP] = f2bf(h2 - bf2f(hi));
        if (layer == 1) {
            const int tout = dir ? (NT - 1 - u) : u;
            out[((size_t)b * NT + tout) * (2 * NH) + dir * NH + j] = h2;   // f32 store
            if (u == NT - 1)
                out[(size_t)NB * NT * (2 * NH) + (size_t)b * (2 * NH) + dir * NH + j] = h2;
        }
    }
}

extern "C" void kernel_launch(void* const* d_in, const int* in_sizes, int n_in,
                              void* d_out, int out_size, void* d_ws, size_t ws_size,
                              hipStream_t stream) {
    (void)in_sizes; (void)n_in; (void)out_size; (void)ws_size;
    const float* x     = (const float*)d_in[0];
    const int*   len   = (const int*)d_in[1];
    const float* fw_Wx = (const float*)d_in[2];
    const float* fw_Wh = (const float*)d_in[3];
    const float* fw_b  = (const float*)d_in[4];
    const float* bw_Wx = (const float*)d_in[5];
    const float* bw_Wh = (const float*)d_in[6];
    const float* bw_b  = (const float*)d_in[7];
    float* out = (float*)d_out;                     // reference output dtype = float32

    char* ws = (char*)d_ws;
    size_t off = 0;
    unsigned short* WT  = (unsigned short*)(ws + off); off += (size_t)2 * 4 * G4 * K2 * 2; // 128 MB (hi+lo)
    unsigned short* xhi = (unsigned short*)(ws + off); off += (size_t)NB * NT * ND * 2;    // 32 MB
    unsigned short* xlo = (unsigned short*)(ws + off); off += (size_t)NB * NT * ND * 2;    // 32 MB
    float* c_state = (float*)(ws + off); off += (size_t)4 * NB * NH * 4;                   // 1 MB
    float* h_f32   = (float*)(ws + off); off += (size_t)4 * NB * NH * 4;                   // 1 MB
    unsigned short* h_bf = (unsigned short*)(ws + off);                                    // 2 MB

    // zero states (c_state, h_f32, h_bf contiguous = 4 MB)
    const size_t zero_bytes = (size_t)4 * NB * NH * 4 * 2 + (size_t)4 * 2 * 2 * NB * NH * 2;
    hipMemsetAsync(c_state, 0, zero_bytes, stream);

    cvt_x<<<(NB * NT * ND) / (256 * 4), 256, 0, stream>>>(x, xhi, xlo);

    dim3 tg(G4 / 64, ND / 64, 8);
    transpose_pack<<<tg, 256, 0, stream>>>(fw_Wx, fw_Wh, bw_Wx, bw_Wh, WT);

    dim3 grid(NH / 16, 4, 1);
    for (int s = 0; s <= NT; ++s) {
        lstm_step<<<grid, 512, 0, stream>>>(s, xhi, xlo, len, fw_b, bw_b, WT,
                                            c_state, h_f32, h_bf, out);
    }
}

// Round 5
// 17931.195 us; speedup vs baseline: 1.2799x; 1.2799x over previous
//
#include <hip/hip_runtime.h>

#define NB 64
#define NT 256
#define ND 1024
#define NH 1024
#define G4 4096
#define K2 2048
// packed B region: per (combo, jpanel, gate): [kk=0..63][plane=hi/lo][lane=0..63][8]
// region elements = 64 * 2 * 64 * 8 = 65536 (128 KB), 1024 regions = 128 MB
#define REG_ELEMS 65536

typedef short v8s __attribute__((ext_vector_type(8)));
typedef float v4f __attribute__((ext_vector_type(4)));
typedef unsigned short us4 __attribute__((ext_vector_type(4)));

__device__ __forceinline__ float bf2f(unsigned short u) {
    union { unsigned int i; float f; } v; v.i = ((unsigned int)u) << 16; return v.f;
}
__device__ __forceinline__ unsigned short f2bf(float f) {
    union { float f; unsigned int i; } v; v.f = f;
    unsigned int x = v.i;
    return (unsigned short)((x + 0x7FFFu + ((x >> 16) & 1u)) >> 16);
}

// ---- one-time: convert x (f32) -> bf16 hi/lo planes ----
__global__ void cvt_x(const float* __restrict__ x,
                      unsigned short* __restrict__ xhi,
                      unsigned short* __restrict__ xlo) {
    const int i = (blockIdx.x * blockDim.x + threadIdx.x) * 4;   // 16,777,216 exact
    const float4 a = *(const float4*)(x + i);
    us4 h, l;
    h.x = f2bf(a.x); l.x = f2bf(a.x - bf2f(h.x));
    h.y = f2bf(a.y); l.y = f2bf(a.y - bf2f(h.y));
    h.z = f2bf(a.z); l.z = f2bf(a.z - bf2f(h.z));
    h.w = f2bf(a.w); l.w = f2bf(a.w - bf2f(h.w));
    *(us4*)(xhi + i) = h;
    *(us4*)(xlo + i) = l;
}

// ---- one-time weight pack into wave-consumption-order regions ----
// combo: 0=fw L0, 1=bw L0, 2=fw L1, 3=bw L1;  k_global = [Wx 0..1023 | Wh 1024..2047]
// element addr = region(c,p,gt)*65536 + kk*1024 + plane*512 + lane*8 + e
//   where lane = g*16 + l15,  k_global = kk*32 + g*8 + e,  n = gt*1024 + p*16 + l15
__global__ void transpose_pack(const float* __restrict__ fw_Wx,
                               const float* __restrict__ fw_Wh,
                               const float* __restrict__ bw_Wx,
                               const float* __restrict__ bw_Wh,
                               unsigned short* __restrict__ WT) {
    const int z = blockIdx.z;
    const int combo = z >> 1;
    const int half  = z & 1;               // 0 -> Wx, 1 -> Wh
    const int layer = combo >> 1, dirb = combo & 1;
    const float* src = half ? (dirb ? bw_Wh : fw_Wh) : (dirb ? bw_Wx : fw_Wx);
    src += (size_t)layer * ND * G4;
    const int n0 = blockIdx.x * 64, k0 = blockIdx.y * 64;
    __shared__ float tile[64][65];
    const int t = threadIdx.x;             // 256 threads
    #pragma unroll
    for (int it = 0; it < 4; ++it) {
        const int kr = it * 16 + (t >> 4);
        const int nc = (t & 15) * 4;
        const float4 v = *(const float4*)(src + (size_t)(k0 + kr) * G4 + n0 + nc);
        tile[kr][nc + 0] = v.x; tile[kr][nc + 1] = v.y;
        tile[kr][nc + 2] = v.z; tile[kr][nc + 3] = v.w;
    }
    __syncthreads();
    #pragma unroll
    for (int it = 0; it < 4; ++it) {
        const int nr = it * 16 + (t >> 4);
        const int kc = (t & 15) * 4;       // k within tile, multiple of 4
        us4 h, l;
        const float w0 = tile[kc + 0][nr], w1 = tile[kc + 1][nr];
        const float w2 = tile[kc + 2][nr], w3 = tile[kc + 3][nr];
        h.x = f2bf(w0); l.x = f2bf(w0 - bf2f(h.x));
        h.y = f2bf(w1); l.y = f2bf(w1 - bf2f(h.y));
        h.z = f2bf(w2); l.z = f2bf(w2 - bf2f(h.z));
        h.w = f2bf(w3); l.w = f2bf(w3 - bf2f(h.w));
        const int n = n0 + nr;             // 0..4095
        const int kg = half * 1024 + k0 + kc;  // 0..2047
        const int gt = n >> 10, j = n & 1023;
        const int p = j >> 4, l15 = j & 15;
        const int kk = kg >> 5, g = (kg >> 3) & 3, e0 = kg & 7;  // e0 in {0,4}
        const int lane = g * 16 + l15;
        const size_t r = ((size_t)combo * 64 + p) * 4 + gt;
        const size_t addr = r * REG_ELEMS + (size_t)kk * 1024 + lane * 8 + e0;
        *(us4*)(WT + addr) = h;            // plane 0 (hi)
        *(us4*)(WT + addr + 512) = l;      // plane 1 (lo)
    }
}

// ---- one super-step: combos {fw0,bw0} at scan step s, {fw1,bw1} at s-1 ----
// h_bf layout: [combo][parity][plane hi/lo][B][H]
__launch_bounds__(512)
__global__ void lstm_step(int s,
                          const unsigned short* __restrict__ xhi,
                          const unsigned short* __restrict__ xlo,
                          const int* __restrict__ lengths,
                          const float* __restrict__ fw_b,
                          const float* __restrict__ bw_b,
                          const unsigned short* __restrict__ WT,
                          float* __restrict__ c_state,              // [4][B][H]
                          float* __restrict__ h_f32,                // [4][B][H]
                          unsigned short* __restrict__ h_bf,        // [4][2][2][B][H]
                          float* __restrict__ out) {
    const int c = blockIdx.y;               // combo
    const int layer = c >> 1, dir = c & 1;
    if (layer == 0) { if (s >= NT) return; }
    else            { if (s < 1)   return; }
    const int u = (layer == 0) ? s : (s - 1);

    const int j0 = blockIdx.x * 16;
    const int tid = threadIdx.x;
    const int w = tid >> 6, lane = tid & 63;
    const int gt = w & 3, mh = w >> 2;
    const int l15 = lane & 15, g = lane >> 4;

    const int n0 = gt * NH + j0;
    const int rowb0 = mh * 32 + l15;
    const int rowb1 = rowb0 + 16;
    const size_t HP = (size_t)NB * NH;      // plane size

    // part-1 A sources (x for layer 0, layer-0 h for layer 1)
    const unsigned short *a0h, *a0l, *a1h, *a1l;
    if (layer == 0) {
        const int t = dir ? (NT - 1 - u) : u;
        const size_t o0 = (size_t)rowb0 * (NT * ND) + (size_t)t * ND + g * 8;
        const size_t o1 = (size_t)rowb1 * (NT * ND) + (size_t)t * ND + g * 8;
        a0h = xhi + o0; a0l = xlo + o0;
        a1h = xhi + o1; a1l = xlo + o1;
    } else {
        const unsigned short* ph = h_bf + (((size_t)dir * 2 + (s & 1)) * 2) * HP;
        a0h = ph + (size_t)rowb0 * NH + g * 8; a0l = a0h + HP;
        a1h = ph + (size_t)rowb1 * NH + g * 8; a1l = a1h + HP;
    }
    // part-2 A sources (own recurrent h)
    const unsigned short* ph2 = h_bf + (((size_t)c * 2 + (u & 1)) * 2) * HP;
    const unsigned short* b0h = ph2 + (size_t)rowb0 * NH + g * 8;
    const unsigned short* b0l = b0h + HP;
    const unsigned short* b1h = ph2 + (size_t)rowb1 * NH + g * 8;
    const unsigned short* b1l = b1h + HP;

    // packed B stream: contiguous 128 KB per (combo, jpanel, gate)
    const unsigned short* bp = WT
        + (((size_t)c * 64 + blockIdx.x) * 4 + gt) * REG_ELEMS
        + (size_t)lane * 8;

    v4f acc0 = {0.f, 0.f, 0.f, 0.f}, acc1 = {0.f, 0.f, 0.f, 0.f};
    #pragma unroll 4
    for (int kk = 0; kk < 32; ++kk) {       // part 1, K = 1024
        v8s ah0 = *(const v8s*)a0h, al0 = *(const v8s*)a0l;
        v8s ah1 = *(const v8s*)a1h, al1 = *(const v8s*)a1l;
        v8s bh  = *(const v8s*)bp,  bl  = *(const v8s*)(bp + 512);
        acc0 = __builtin_amdgcn_mfma_f32_16x16x32_bf16(ah0, bh, acc0, 0, 0, 0);
        acc1 = __builtin_amdgcn_mfma_f32_16x16x32_bf16(ah1, bh, acc1, 0, 0, 0);
        acc0 = __builtin_amdgcn_mfma_f32_16x16x32_bf16(ah0, bl, acc0, 0, 0, 0);
        acc1 = __builtin_amdgcn_mfma_f32_16x16x32_bf16(ah1, bl, acc1, 0, 0, 0);
        acc0 = __builtin_amdgcn_mfma_f32_16x16x32_bf16(al0, bh, acc0, 0, 0, 0);
        acc1 = __builtin_amdgcn_mfma_f32_16x16x32_bf16(al1, bh, acc1, 0, 0, 0);
        a0h += 32; a0l += 32; a1h += 32; a1l += 32; bp += 1024;
    }
    #pragma unroll 4
    for (int kk = 0; kk < 32; ++kk) {       // part 2 (recurrent), K = 1024
        v8s ah0 = *(const v8s*)b0h, al0 = *(const v8s*)b0l;
        v8s ah1 = *(const v8s*)b1h, al1 = *(const v8s*)b1l;
        v8s bh  = *(const v8s*)bp,  bl  = *(const v8s*)(bp + 512);
        acc0 = __builtin_amdgcn_mfma_f32_16x16x32_bf16(ah0, bh, acc0, 0, 0, 0);
        acc1 = __builtin_amdgcn_mfma_f32_16x16x32_bf16(ah1, bh, acc1, 0, 0, 0);
        acc0 = __builtin_amdgcn_mfma_f32_16x16x32_bf16(ah0, bl, acc0, 0, 0, 0);
        acc1 = __builtin_amdgcn_mfma_f32_16x16x32_bf16(ah1, bl, acc1, 0, 0, 0);
        acc0 = __builtin_amdgcn_mfma_f32_16x16x32_bf16(al0, bh, acc0, 0, 0, 0);
        acc1 = __builtin_amdgcn_mfma_f32_16x16x32_bf16(al1, bh, acc1, 0, 0, 0);
        b0h += 32; b0l += 32; b1h += 32; b1l += 32; bp += 1024;
    }

    const float* bsrc = dir ? bw_b : fw_b;
    const float bias = bsrc[(size_t)layer * G4 + n0 + l15];
    #pragma unroll
    for (int r = 0; r < 4; ++r) { acc0[r] += bias; acc1[r] += bias; }

    __shared__ float glds[4][NB][16];
    #pragma unroll
    for (int r = 0; r < 4; ++r) {
        glds[gt][mh * 32 + g * 4 + r][l15]      = acc0[r];
        glds[gt][mh * 32 + 16 + g * 4 + r][l15] = acc1[r];
    }
    __syncthreads();

    for (int e = tid; e < NB * 16; e += 512) {
        const int b = e >> 4, jj = e & 15, j = j0 + jj;
        const float iv = glds[0][b][jj];
        const float fv = glds[1][b][jj];
        const float gv = glds[2][b][jj];
        const float ov = glds[3][b][jj];
        const size_t sidx = ((size_t)c * NB + b) * NH + j;
        const float cold = c_state[sidx];
        const float hold = h_f32[sidx];
        const float si = 1.f / (1.f + expf(-iv));
        const float sf = 1.f / (1.f + expf(-fv));
        const float so = 1.f / (1.f + expf(-ov));
        const float cn = sf * cold + si * tanhf(gv);
        const float hn = so * tanhf(cn);
        const bool valid = lengths[b] > u;     // un-reversed mask (reference quirk)
        const float c2 = valid ? cn : cold;
        const float h2 = valid ? hn : hold;
        c_state[sidx] = c2;
        h_f32[sidx]  = h2;
        const size_t hb = (((size_t)c * 2 + ((u + 1) & 1)) * 2) * HP + (size_t)b * NH + j;
        const unsigned short hi = f2bf(h2);
        h_bf[hb]      = hi;
        h_bf[hb + HP] = f2bf(h2 - bf2f(hi));
        if (layer == 1) {
            const int tout = dir ? (NT - 1 - u) : u;
            out[((size_t)b * NT + tout) * (2 * NH) + dir * NH + j] = h2;   // f32 store
            if (u == NT - 1)
                out[(size_t)NB * NT * (2 * NH) + (size_t)b * (2 * NH) + dir * NH + j] = h2;
        }
    }
}

extern "C" void kernel_launch(void* const* d_in, const int* in_sizes, int n_in,
                              void* d_out, int out_size, void* d_ws, size_t ws_size,
                              hipStream_t stream) {
    (void)in_sizes; (void)n_in; (void)out_size; (void)ws_size;
    const float* x     = (const float*)d_in[0];
    const int*   len   = (const int*)d_in[1];
    const float* fw_Wx = (const float*)d_in[2];
    const float* fw_Wh = (const float*)d_in[3];
    const float* fw_b  = (const float*)d_in[4];
    const float* bw_Wx = (const float*)d_in[5];
    const float* bw_Wh = (const float*)d_in[6];
    const float* bw_b  = (const float*)d_in[7];
    float* out = (float*)d_out;                     // reference output dtype = float32

    char* ws = (char*)d_ws;
    size_t off = 0;
    unsigned short* WT  = (unsigned short*)(ws + off); off += (size_t)1024 * REG_ELEMS * 2;  // 128 MB
    unsigned short* xhi = (unsigned short*)(ws + off); off += (size_t)NB * NT * ND * 2;      // 32 MB
    unsigned short* xlo = (unsigned short*)(ws + off); off += (size_t)NB * NT * ND * 2;      // 32 MB
    float* c_state = (float*)(ws + off); off += (size_t)4 * NB * NH * 4;                     // 1 MB
    float* h_f32   = (float*)(ws + off); off += (size_t)4 * NB * NH * 4;                     // 1 MB
    unsigned short* h_bf = (unsigned short*)(ws + off);                                      // 2 MB

    // zero states (c_state, h_f32, h_bf contiguous = 4 MB)
    const size_t zero_bytes = (size_t)4 * NB * NH * 4 * 2 + (size_t)4 * 2 * 2 * NB * NH * 2;
    hipMemsetAsync(c_state, 0, zero_bytes, stream);

    cvt_x<<<(NB * NT * ND) / (256 * 4), 256, 0, stream>>>(x, xhi, xlo);

    dim3 tg(G4 / 64, ND / 64, 8);
    transpose_pack<<<tg, 256, 0, stream>>>(fw_Wx, fw_Wh, bw_Wx, bw_Wh, WT);

    dim3 grid(NH / 16, 4, 1);
    for (int s = 0; s <= NT; ++s) {
        lstm_step<<<grid, 512, 0, stream>>>(s, xhi, xlo, len, fw_b, bw_b, WT,
                                            c_state, h_f32, h_bf, out);
    }
}